// Round 1
// baseline (290.048 us; speedup 1.0000x reference)
//
#include <hip/hip_runtime.h>

#define N_NODES 50000
#define N_EDGES 800000
#define DIM 128

// ---------------- CSR build ----------------

__global__ void zero_counts_k(int* __restrict__ count, int* __restrict__ cursor) {
    int i = blockIdx.x * blockDim.x + threadIdx.x;
    if (i < N_NODES) { count[i] = 0; cursor[i] = 0; }
}

__global__ void degree_k(const int* __restrict__ dst, int* __restrict__ count) {
    int e = blockIdx.x * blockDim.x + threadIdx.x;
    if (e < N_EDGES) atomicAdd(&count[dst[e]], 1);
}

// Per-block exclusive scan of count -> offs (local), block totals -> bsum
__global__ void scanA_k(const int* __restrict__ count, int* __restrict__ offs,
                        int* __restrict__ bsum) {
    __shared__ int lds[256];
    int t = threadIdx.x;
    int i = blockIdx.x * 256 + t;
    int v = (i < N_NODES) ? count[i] : 0;
    lds[t] = v;
    __syncthreads();
    for (int s = 1; s < 256; s <<= 1) {
        int add = (t >= s) ? lds[t - s] : 0;
        __syncthreads();
        lds[t] += add;
        __syncthreads();
    }
    if (i < N_NODES) offs[i] = lds[t] - v;  // exclusive
    if (t == 255) bsum[blockIdx.x] = lds[255];
}

// Single-block exclusive scan of bsum in place (nb <= 256)
__global__ void scanB_k(int* __restrict__ bsum, int nb) {
    __shared__ int lds[256];
    int t = threadIdx.x;
    int v = (t < nb) ? bsum[t] : 0;
    lds[t] = v;
    __syncthreads();
    for (int s = 1; s < 256; s <<= 1) {
        int add = (t >= s) ? lds[t - s] : 0;
        __syncthreads();
        lds[t] += add;
        __syncthreads();
    }
    if (t < nb) bsum[t] = lds[t] - v;
}

__global__ void scanC_k(int* __restrict__ offs, const int* __restrict__ bsum) {
    int i = blockIdx.x * 256 + threadIdx.x;
    if (i < N_NODES) offs[i] += bsum[blockIdx.x];
}

__global__ void fill_k(const int* __restrict__ src, const int* __restrict__ dst,
                       const int* __restrict__ offs, int* __restrict__ cursor,
                       int* __restrict__ srclist) {
    int e = blockIdx.x * blockDim.x + threadIdx.x;
    if (e < N_EDGES) {
        int d = dst[e];
        int pos = atomicAdd(&cursor[d], 1);
        srclist[offs[d] + pos] = src[e];
    }
}

// ---------------- Aggregate: one wave per node, no fp atomics ----------------
// neigh[i] = (1/max(deg,1)) * sum_{e: dst[e]==i} x[src[e]]
__global__ void agg_k(const float* __restrict__ x, const int* __restrict__ offs,
                      const int* __restrict__ count, const int* __restrict__ srclist,
                      float* __restrict__ neigh) {
    int wid  = (blockIdx.x * blockDim.x + threadIdx.x) >> 6;  // wave id = node
    int lane = threadIdx.x & 63;
    if (wid >= N_NODES) return;
    int off = offs[wid];
    int deg = count[wid];
    float2 acc = make_float2(0.f, 0.f);
    for (int base = 0; base < deg; base += 64) {
        int m = deg - base;
        if (m > 64) m = 64;
        int sreg = (lane < m) ? srclist[off + base + lane] : 0;
        for (int j = 0; j < m; ++j) {
            int s = __shfl(sreg, j);  // uniform -> scalar base address
            float2 v = *(const float2*)(x + (size_t)s * DIM + lane * 2);
            acc.x += v.x;
            acc.y += v.y;
        }
    }
    float scale = 1.0f / (float)(deg > 0 ? deg : 1);
    float2 r = make_float2(acc.x * scale, acc.y * scale);
    *((float2*)(neigh + (size_t)wid * DIM) + lane) = r;
}

// ---------------- Fused GEMM: out = x@Ws^T + b + neigh@Wn^T ----------------
// Per block: 64 rows x 128 cols. 256 threads, thread tile 8 rows x 4 cols.
// A = [x | neigh] (K=256) staged in LDS; W rows read from global (L2-resident).
__global__ __launch_bounds__(256) void gemm_k(
    const float* __restrict__ x, const float* __restrict__ neigh,
    const float* __restrict__ Ws, const float* __restrict__ Wn,
    const float* __restrict__ b, float* __restrict__ out) {
    __shared__ float a_lds[64][256];  // 64 KB
    int tid  = threadIdx.x;
    int row0 = blockIdx.x * 64;

    // Stage A-tile: 4096 float4s, 16 per thread
    for (int it = 0; it < 16; ++it) {
        int flat = it * 256 + tid;
        int row  = flat >> 6;       // 0..63
        int k    = (flat & 63) * 4; // 0..252
        int grow = row0 + row;
        float4 v = make_float4(0.f, 0.f, 0.f, 0.f);
        if (grow < N_NODES) {
            v = (k < 128) ? *(const float4*)(x + (size_t)grow * 128 + k)
                          : *(const float4*)(neigh + (size_t)grow * 128 + (k - 128));
        }
        *(float4*)(&a_lds[row][k]) = v;
    }
    __syncthreads();

    int jt = tid & 31;   // 32 col-tiles of 4
    int rg = tid >> 5;   // 8 row-groups of 8
    int j0 = jt * 4;

    float acc[8][4];
#pragma unroll
    for (int m = 0; m < 8; ++m)
#pragma unroll
        for (int n = 0; n < 4; ++n) acc[m][n] = 0.f;

    // First half: k in [0,128) uses Ws; second half uses Wn.
#pragma unroll 1
    for (int half = 0; half < 2; ++half) {
        const float* __restrict__ W = (half == 0) ? Ws : Wn;
        int kbase = half * 128;
#pragma unroll 4
        for (int k4 = 0; k4 < 32; ++k4) {
            int k = k4 * 4;  // within-half k
            float4 w[4];
#pragma unroll
            for (int n = 0; n < 4; ++n)
                w[n] = *(const float4*)(W + (size_t)(j0 + n) * 128 + k);
            float4 a[8];
#pragma unroll
            for (int m = 0; m < 8; ++m)
                a[m] = *(const float4*)(&a_lds[rg * 8 + m][kbase + k]);
#pragma unroll
            for (int m = 0; m < 8; ++m)
#pragma unroll
                for (int n = 0; n < 4; ++n) {
                    acc[m][n] += a[m].x * w[n].x + a[m].y * w[n].y +
                                 a[m].z * w[n].z + a[m].w * w[n].w;
                }
        }
    }

    float4 bias = *(const float4*)(b + j0);
#pragma unroll
    for (int m = 0; m < 8; ++m) {
        int row = row0 + rg * 8 + m;
        if (row < N_NODES) {
            float4 r = make_float4(acc[m][0] + bias.x, acc[m][1] + bias.y,
                                   acc[m][2] + bias.z, acc[m][3] + bias.w);
            *(float4*)(out + (size_t)row * 128 + j0) = r;
        }
    }
}

extern "C" void kernel_launch(void* const* d_in, const int* in_sizes, int n_in,
                              void* d_out, int out_size, void* d_ws, size_t ws_size,
                              hipStream_t stream) {
    const float* x      = (const float*)d_in[0];
    const float* W_self = (const float*)d_in[1];
    const float* b_self = (const float*)d_in[2];
    const float* W_neigh= (const float*)d_in[3];
    // d_in[4] = edge_w: unused — it equals 1/max(deg(dst),1), recomputed from counts
    const int*   src    = (const int*)d_in[5];
    const int*   dst    = (const int*)d_in[6];
    float* out = (float*)d_out;

    // ws layout (bytes): neigh | count | cursor | offs | bsum | srclist  (~29.5 MB)
    char* ws = (char*)d_ws;
    float* neigh  = (float*)(ws);                         // 25,600,000 B
    int*   count  = (int*)(ws + 25600000);                // 200,000 B
    int*   cursor = (int*)(ws + 25800000);                // 200,000 B
    int*   offs   = (int*)(ws + 26000000);                // 200,000 B
    int*   bsum   = (int*)(ws + 26200000);                // 1,024 B
    int*   srclist= (int*)(ws + 26201088);                // 3,200,000 B

    const int nscan = (N_NODES + 255) / 256;   // 196
    const int nedge = (N_EDGES + 255) / 256;   // 3125

    zero_counts_k<<<nscan, 256, 0, stream>>>(count, cursor);
    degree_k<<<nedge, 256, 0, stream>>>(dst, count);
    scanA_k<<<nscan, 256, 0, stream>>>(count, offs, bsum);
    scanB_k<<<1, 256, 0, stream>>>(bsum, nscan);
    scanC_k<<<nscan, 256, 0, stream>>>(offs, bsum);
    fill_k<<<nedge, 256, 0, stream>>>(src, dst, offs, cursor, srclist);

    // aggregate: one wave per node, 4 waves per block
    agg_k<<<(N_NODES + 3) / 4, 256, 0, stream>>>(x, offs, count, srclist, neigh);

    // fused dense part
    gemm_k<<<(N_NODES + 63) / 64, 256, 0, stream>>>(x, neigh, W_self, W_neigh, b_self, out);
}

// Round 2
// 176.485 us; speedup vs baseline: 1.6435x; 1.6435x over previous
//
#include <hip/hip_runtime.h>
#include <hip/hip_bf16.h>

#define N_NODES 50000
#define N_EDGES 800000
#define DIM 128

typedef __attribute__((ext_vector_type(8))) short bf16x8;
typedef __attribute__((ext_vector_type(4))) float f32x4;

static __device__ __forceinline__ ushort f2bf(float f) {
    __hip_bfloat16 h = __float2bfloat16(f);
    return *reinterpret_cast<ushort*>(&h);
}
static __device__ __forceinline__ uint pack2(float a, float b) {
    return (uint)f2bf(a) | ((uint)f2bf(b) << 16);
}
static __device__ __forceinline__ float bflo(uint u) { return __uint_as_float(u << 16); }
static __device__ __forceinline__ float bfhi(uint u) { return __uint_as_float(u & 0xffff0000u); }

// ---------------- fp32 -> bf16 conversions ----------------

__global__ void cvt_k(const float* __restrict__ in, ushort* __restrict__ outp, int n8) {
    int t = blockIdx.x * blockDim.x + threadIdx.x;
    if (t >= n8) return;
    int i = t * 8;
    float4 a = *(const float4*)(in + i);
    float4 b = *(const float4*)(in + i + 4);
    uint4 r;
    r.x = pack2(a.x, a.y); r.y = pack2(a.z, a.w);
    r.z = pack2(b.x, b.y); r.w = pack2(b.z, b.w);
    *(uint4*)(outp + i) = r;
}

// Wcat = [Ws ; Wn] as bf16 (256 rows x 128 cols, row-major)
__global__ void cvtW_k(const float* __restrict__ Ws, const float* __restrict__ Wn,
                       ushort* __restrict__ Wcat) {
    int t = blockIdx.x * blockDim.x + threadIdx.x;  // 0..4095
    const float* srcp = (t < 2048) ? Ws : Wn;
    int i = (t & 2047) * 8;
    float4 a = *(const float4*)(srcp + i);
    float4 b = *(const float4*)(srcp + i + 4);
    uint4 r;
    r.x = pack2(a.x, a.y); r.y = pack2(a.z, a.w);
    r.z = pack2(b.x, b.y); r.w = pack2(b.z, b.w);
    *(uint4*)(Wcat + ((t < 2048) ? 0 : 16384) + i) = r;
}

// ---------------- CSR build ----------------

__global__ void degree_k(const int* __restrict__ dst, int* __restrict__ count) {
    int e = blockIdx.x * blockDim.x + threadIdx.x;
    if (e < N_EDGES) atomicAdd(&count[dst[e]], 1);
}

__global__ void scanA_k(const int* __restrict__ count, int* __restrict__ offs,
                        int* __restrict__ bsum) {
    __shared__ int lds[256];
    int t = threadIdx.x;
    int i = blockIdx.x * 256 + t;
    int v = (i < N_NODES) ? count[i] : 0;
    lds[t] = v;
    __syncthreads();
    for (int s = 1; s < 256; s <<= 1) {
        int add = (t >= s) ? lds[t - s] : 0;
        __syncthreads();
        lds[t] += add;
        __syncthreads();
    }
    if (i < N_NODES) offs[i] = lds[t] - v;
    if (t == 255) bsum[blockIdx.x] = lds[255];
}

__global__ void scanB_k(int* __restrict__ bsum, int nb) {
    __shared__ int lds[256];
    int t = threadIdx.x;
    int v = (t < nb) ? bsum[t] : 0;
    lds[t] = v;
    __syncthreads();
    for (int s = 1; s < 256; s <<= 1) {
        int add = (t >= s) ? lds[t - s] : 0;
        __syncthreads();
        lds[t] += add;
        __syncthreads();
    }
    if (t < nb) bsum[t] = lds[t] - v;
}

__global__ void scanC_k(int* __restrict__ offs, const int* __restrict__ bsum) {
    int i = blockIdx.x * 256 + threadIdx.x;
    if (i < N_NODES) offs[i] += bsum[blockIdx.x];
}

__global__ void fill_k(const int* __restrict__ src, const int* __restrict__ dst,
                       const int* __restrict__ offs, int* __restrict__ cursor,
                       int* __restrict__ srclist) {
    int e = blockIdx.x * blockDim.x + threadIdx.x;
    if (e < N_EDGES) {
        int d = dst[e];
        int pos = atomicAdd(&cursor[d], 1);
        srclist[offs[d] + pos] = src[e];
    }
}

// ---------------- MFMA GEMM: Y = x @ [Ws|Wn]^T ----------------
// One wave per 16 rows; no LDS. A/B frags are direct 16B loads
// (mfma_f32_16x16x32_bf16: lane holds row/col = lane&15, k = (lane>>4)*8 + j).
// cols 0..127 -> out (fp32, +bias); cols 128..255 -> Yn (bf16).
__global__ __launch_bounds__(256) void mm_k(const ushort* __restrict__ xb,
                                            const ushort* __restrict__ Wcat,
                                            const float* __restrict__ bias,
                                            float* __restrict__ out,
                                            ushort* __restrict__ Yn) {
    int wid = blockIdx.x * 4 + (threadIdx.x >> 6);
    if (wid >= N_NODES / 16) return;  // 3125 waves
    int lane = threadIdx.x & 63;
    int lr = lane & 15;
    int lk = (lane >> 4) * 8;
    int r0 = wid * 16;
    const ushort* ap = xb + (size_t)(r0 + lr) * 128 + lk;
    bf16x8 a0 = *(const bf16x8*)(ap);
    bf16x8 a1 = *(const bf16x8*)(ap + 32);
    bf16x8 a2 = *(const bf16x8*)(ap + 64);
    bf16x8 a3 = *(const bf16x8*)(ap + 96);
    int rowb = r0 + (lane >> 4) * 4;

#pragma unroll
    for (int nt = 0; nt < 16; nt += 2) {
        const ushort* bp0 = Wcat + (size_t)(nt * 16 + lr) * 128 + lk;
        const ushort* bp1 = bp0 + 16 * 128;
        bf16x8 b00 = *(const bf16x8*)(bp0);
        bf16x8 b01 = *(const bf16x8*)(bp0 + 32);
        bf16x8 b02 = *(const bf16x8*)(bp0 + 64);
        bf16x8 b03 = *(const bf16x8*)(bp0 + 96);
        bf16x8 b10 = *(const bf16x8*)(bp1);
        bf16x8 b11 = *(const bf16x8*)(bp1 + 32);
        bf16x8 b12 = *(const bf16x8*)(bp1 + 64);
        bf16x8 b13 = *(const bf16x8*)(bp1 + 96);
        f32x4 c0 = {0.f, 0.f, 0.f, 0.f};
        f32x4 c1 = {0.f, 0.f, 0.f, 0.f};
        c0 = __builtin_amdgcn_mfma_f32_16x16x32_bf16(a0, b00, c0, 0, 0, 0);
        c1 = __builtin_amdgcn_mfma_f32_16x16x32_bf16(a0, b10, c1, 0, 0, 0);
        c0 = __builtin_amdgcn_mfma_f32_16x16x32_bf16(a1, b01, c0, 0, 0, 0);
        c1 = __builtin_amdgcn_mfma_f32_16x16x32_bf16(a1, b11, c1, 0, 0, 0);
        c0 = __builtin_amdgcn_mfma_f32_16x16x32_bf16(a2, b02, c0, 0, 0, 0);
        c1 = __builtin_amdgcn_mfma_f32_16x16x32_bf16(a2, b12, c1, 0, 0, 0);
        c0 = __builtin_amdgcn_mfma_f32_16x16x32_bf16(a3, b03, c0, 0, 0, 0);
        c1 = __builtin_amdgcn_mfma_f32_16x16x32_bf16(a3, b13, c1, 0, 0, 0);

        // epilogue for both n-tiles
        {
            int col = nt * 16 + lr;
            float bv = bias[col];  // nt<8 => col<128 always here? no: guard below
            if (col < 128) {
#pragma unroll
                for (int j = 0; j < 4; ++j)
                    out[(size_t)(rowb + j) * 128 + col] = c0[j] + bv;
            } else {
                int cc = col - 128;
#pragma unroll
                for (int j = 0; j < 4; ++j)
                    Yn[(size_t)(rowb + j) * 128 + cc] = f2bf(c0[j]);
            }
        }
        {
            int col = (nt + 1) * 16 + lr;
            if (col < 128) {
                float bv = bias[col];
#pragma unroll
                for (int j = 0; j < 4; ++j)
                    out[(size_t)(rowb + j) * 128 + col] = c1[j] + bv;
            } else {
                int cc = col - 128;
#pragma unroll
                for (int j = 0; j < 4; ++j)
                    Yn[(size_t)(rowb + j) * 128 + cc] = f2bf(c1[j]);
            }
        }
    }
}

// ---------------- Aggregate: out[v] += (1/deg) * sum Yn[src] ----------------
// One wave per node; 16 lanes x 16B cover a 256B bf16 row -> 4 edges/iter.
__global__ __launch_bounds__(256) void agg2_k(const ushort* __restrict__ Yn,
                                              const int* __restrict__ offs,
                                              const int* __restrict__ count,
                                              const int* __restrict__ srclist,
                                              float* __restrict__ out) {
    int wid = blockIdx.x * 4 + (threadIdx.x >> 6);
    if (wid >= N_NODES) return;
    int lane = threadIdx.x & 63;
    int g = lane >> 4;          // edge slot within quad
    int c8 = (lane & 15) * 8;   // col base (8 bf16 = 16B)
    int off = offs[wid];
    int deg = count[wid];

    float acc0 = 0.f, acc1 = 0.f, acc2 = 0.f, acc3 = 0.f;
    float acc4 = 0.f, acc5 = 0.f, acc6 = 0.f, acc7 = 0.f;

#define ACC8(v)                                        \
    do {                                               \
        acc0 += bflo(v.x); acc1 += bfhi(v.x);          \
        acc2 += bflo(v.y); acc3 += bfhi(v.y);          \
        acc4 += bflo(v.z); acc5 += bfhi(v.z);          \
        acc6 += bflo(v.w); acc7 += bfhi(v.w);          \
    } while (0)

    for (int cb = 0; cb < deg; cb += 64) {
        int m = deg - cb;
        if (m > 64) m = 64;
        int sreg = (lane < m) ? srclist[off + cb + lane] : 0;
        int j = 0;
        for (; j + 4 <= m; j += 4) {
            int s = __shfl(sreg, j + g);
            uint4 v = *(const uint4*)(Yn + (size_t)s * 128 + c8);
            ACC8(v);
        }
        if (j < m) {
            int jj = j + g;
            bool valid = jj < m;
            int s = __shfl(sreg, valid ? jj : j);
            uint4 v = *(const uint4*)(Yn + (size_t)s * 128 + c8);
            if (valid) ACC8(v);
        }
    }
#undef ACC8

    // reduce the 4 edge-slot groups
#define RED(a) do { a += __shfl_xor(a, 16); a += __shfl_xor(a, 32); } while (0)
    RED(acc0); RED(acc1); RED(acc2); RED(acc3);
    RED(acc4); RED(acc5); RED(acc6); RED(acc7);
#undef RED

    if (lane < 16) {
        float scale = 1.0f / (float)(deg > 0 ? deg : 1);
        float* orow = out + (size_t)wid * 128 + c8;
        float4 o0 = *(const float4*)(orow);
        float4 o1 = *(const float4*)(orow + 4);
        o0.x += scale * acc0; o0.y += scale * acc1;
        o0.z += scale * acc2; o0.w += scale * acc3;
        o1.x += scale * acc4; o1.y += scale * acc5;
        o1.z += scale * acc6; o1.w += scale * acc7;
        *(float4*)(orow) = o0;
        *(float4*)(orow + 4) = o1;
    }
}

extern "C" void kernel_launch(void* const* d_in, const int* in_sizes, int n_in,
                              void* d_out, int out_size, void* d_ws, size_t ws_size,
                              hipStream_t stream) {
    const float* x       = (const float*)d_in[0];
    const float* W_self  = (const float*)d_in[1];
    const float* b_self  = (const float*)d_in[2];
    const float* W_neigh = (const float*)d_in[3];
    // d_in[4] = edge_w: unused (== 1/max(deg(dst),1), recomputed from counts)
    const int* src = (const int*)d_in[5];
    const int* dst = (const int*)d_in[6];
    float* out = (float*)d_out;

    // ws layout (bytes)
    char* ws = (char*)d_ws;
    ushort* xb     = (ushort*)(ws);              // 12,800,000
    ushort* Yn     = (ushort*)(ws + 12800000);   // 12,800,000
    ushort* Wcat   = (ushort*)(ws + 25600000);   //     65,536
    int*    count  = (int*)(ws + 25665536);      //    200,000
    int*    cursor = (int*)(ws + 25865536);      //    200,000
    int*    offs   = (int*)(ws + 26065536);      //    200,000
    int*    bsum   = (int*)(ws + 26265536);      //      1,024
    int*    srclist= (int*)(ws + 26266560);      //  3,200,000

    const int nscan = (N_NODES + 255) / 256;  // 196
    const int nedge = (N_EDGES + 255) / 256;  // 3125

    // zero count+cursor (contiguous) in one memset
    hipMemsetAsync(count, 0, 400000, stream);

    cvt_k<<<3125, 256, 0, stream>>>(x, xb, 800000);
    cvtW_k<<<16, 256, 0, stream>>>(W_self, W_neigh, Wcat);

    degree_k<<<nedge, 256, 0, stream>>>(dst, count);
    scanA_k<<<nscan, 256, 0, stream>>>(count, offs, bsum);
    scanB_k<<<1, 256, 0, stream>>>(bsum, nscan);
    scanC_k<<<nscan, 256, 0, stream>>>(offs, bsum);
    fill_k<<<nedge, 256, 0, stream>>>(src, dst, offs, cursor, srclist);

    // dense: out = x@Ws^T + b (fp32), Yn = x@Wn^T (bf16)
    mm_k<<<(N_NODES / 16 + 3) / 4, 256, 0, stream>>>(xb, Wcat, b_self, out, Yn);

    // sparse: out[v] += (1/deg) * sum_{src->v} Yn[src]
    agg2_k<<<(N_NODES + 3) / 4, 256, 0, stream>>>(Yn, offs, count, srclist, out);
}

// Round 3
// 119.833 us; speedup vs baseline: 2.4204x; 1.4728x over previous
//
#include <hip/hip_runtime.h>
#include <hip/hip_bf16.h>

#define N_NODES 50000
#define N_EDGES 800000
#define DIM 128

typedef __attribute__((ext_vector_type(8))) short bf16x8;
typedef __attribute__((ext_vector_type(4))) float f32x4;

union BU8 { uint4 u; bf16x8 b; };

static __device__ __forceinline__ ushort f2bf(float f) {
    __hip_bfloat16 h = __float2bfloat16(f);
    return *reinterpret_cast<ushort*>(&h);
}
static __device__ __forceinline__ uint pack2(float a, float b) {
    return (uint)f2bf(a) | ((uint)f2bf(b) << 16);
}
static __device__ __forceinline__ float bflo(uint u) { return __uint_as_float(u << 16); }
static __device__ __forceinline__ float bfhi(uint u) { return __uint_as_float(u & 0xffff0000u); }

// ---------------- W concat + convert: Wcat = [Ws ; Wn] bf16 ----------------
__global__ void cvtW_k(const float* __restrict__ Ws, const float* __restrict__ Wn,
                       ushort* __restrict__ Wcat) {
    int t = blockIdx.x * blockDim.x + threadIdx.x;  // 0..4095
    const float* srcp = (t < 2048) ? Ws : Wn;
    int i = (t & 2047) * 8;
    float4 a = *(const float4*)(srcp + i);
    float4 b = *(const float4*)(srcp + i + 4);
    uint4 r;
    r.x = pack2(a.x, a.y); r.y = pack2(a.z, a.w);
    r.z = pack2(b.x, b.y); r.w = pack2(b.z, b.w);
    *(uint4*)(Wcat + ((t < 2048) ? 0 : 16384) + i) = r;
}

// ---------------- CSR build (atomic-free fill) ----------------

// counts + per-edge slot (unique via atomicAdd return value)
__global__ void degree_k(const int* __restrict__ dst, int* __restrict__ count,
                         ushort* __restrict__ epos) {
    int e = blockIdx.x * blockDim.x + threadIdx.x;
    if (e < N_EDGES) {
        int pos = atomicAdd(&count[dst[e]], 1);
        epos[e] = (ushort)pos;
    }
}

__global__ void scanA_k(const int* __restrict__ count, int* __restrict__ offs,
                        int* __restrict__ bsum) {
    __shared__ int lds[256];
    int t = threadIdx.x;
    int i = blockIdx.x * 256 + t;
    int v = (i < N_NODES) ? count[i] : 0;
    lds[t] = v;
    __syncthreads();
    for (int s = 1; s < 256; s <<= 1) {
        int add = (t >= s) ? lds[t - s] : 0;
        __syncthreads();
        lds[t] += add;
        __syncthreads();
    }
    if (i < N_NODES) offs[i] = lds[t] - v;  // block-local exclusive
    if (t == 255) bsum[blockIdx.x] = lds[255];
}

// every block redundantly scans the 196 block sums, adds its prefix
__global__ void scanBC_k(int* __restrict__ offs, const int* __restrict__ bsum, int nb) {
    __shared__ int lds[256];
    int t = threadIdx.x;
    lds[t] = (t < nb) ? bsum[t] : 0;
    __syncthreads();
    for (int s = 1; s < 256; s <<= 1) {
        int add = (t >= s) ? lds[t - s] : 0;
        __syncthreads();
        lds[t] += add;
        __syncthreads();
    }
    int b = blockIdx.x;
    int prefix = (b == 0) ? 0 : lds[b - 1];
    int i = b * 256 + t;
    if (i < N_NODES) offs[i] += prefix;
}

__global__ void fill_k(const int* __restrict__ src, const int* __restrict__ dst,
                       const int* __restrict__ offs, const ushort* __restrict__ epos,
                       ushort* __restrict__ srclist) {
    int e = blockIdx.x * blockDim.x + threadIdx.x;
    if (e < N_EDGES) {
        int d = dst[e];
        srclist[offs[d] + (int)epos[e]] = (ushort)src[e];
    }
}

// ---------------- MFMA GEMM: out = x@Ws^T + b (fp32), Yn = x@Wn^T (bf16) --
// Block: 256 thr = 4 waves, 128 rows. Wcat (256x128 bf16, 64KB) staged in
// XOR-swizzled LDS once per block. Each wave: 32 rows x 256 cols,
// acc = 2x16 f32x4. A read fp32 from x, converted in-reg.
__global__ __launch_bounds__(256, 2) void mm_k(const float* __restrict__ x,
                                               const ushort* __restrict__ Wcat,
                                               const float* __restrict__ bias,
                                               float* __restrict__ out,
                                               ushort* __restrict__ Yn) {
    __shared__ ushort wlds[32768];  // 64 KB
    int tid  = threadIdx.x;
    int lane = tid & 63;
    int w    = tid >> 6;
    int lr   = lane & 15;
    int g    = lane >> 4;            // k-group 0..3
    int myrow0 = blockIdx.x * 128 + w * 32;

    // ---- load A (fp32) & convert: 2 rowtiles x 4 kfrags ----
    bf16x8 a[2][4];
#pragma unroll
    for (int rt = 0; rt < 2; ++rt) {
        int row = myrow0 + rt * 16 + lr;
        bool ok = row < N_NODES;
        const float* ap = x + (size_t)row * 128;
#pragma unroll
        for (int kf = 0; kf < 4; ++kf) {
            float4 f0 = make_float4(0.f, 0.f, 0.f, 0.f), f1 = f0;
            if (ok) {
                f0 = *(const float4*)(ap + kf * 32 + g * 8);
                f1 = *(const float4*)(ap + kf * 32 + g * 8 + 4);
            }
            BU8 u;
            u.u.x = pack2(f0.x, f0.y); u.u.y = pack2(f0.z, f0.w);
            u.u.z = pack2(f1.x, f1.y); u.u.w = pack2(f1.z, f1.w);
            a[rt][kf] = u.b;
        }
    }

    // ---- stage Wcat into swizzled LDS: chunk c (16B) of row r at c^(r&7) ----
#pragma unroll
    for (int i = 0; i < 16; ++i) {
        int f = i * 256 + tid;
        int r = f >> 4, c = f & 15;
        uint4 v = *(const uint4*)(Wcat + r * 128 + c * 8);
        *(uint4*)(&wlds[r * 128 + ((c ^ (r & 7)) * 8)]) = v;
    }
    __syncthreads();

    // ---- K-loop over 16 col-tiles ----
    f32x4 acc[2][16];
#pragma unroll
    for (int rt = 0; rt < 2; ++rt)
#pragma unroll
        for (int nt = 0; nt < 16; ++nt) acc[rt][nt] = (f32x4){0.f, 0.f, 0.f, 0.f};

#pragma unroll
    for (int nt = 0; nt < 16; ++nt) {
        int row = nt * 16 + lr;
#pragma unroll
        for (int kf = 0; kf < 4; ++kf) {
            int chunk = kf * 4 + g;
            bf16x8 b = *(const bf16x8*)(&wlds[row * 128 + ((chunk ^ (lr & 7)) * 8)]);
            acc[0][nt] = __builtin_amdgcn_mfma_f32_16x16x32_bf16(a[0][kf], b, acc[0][nt], 0, 0, 0);
            acc[1][nt] = __builtin_amdgcn_mfma_f32_16x16x32_bf16(a[1][kf], b, acc[1][nt], 0, 0, 0);
        }
    }

    // ---- epilogue: col<128 -> out(+bias); col>=128 -> Yn bf16 ----
#pragma unroll
    for (int nt = 0; nt < 16; ++nt) {
        int col = nt * 16 + lr;
        float bv = (col < 128) ? bias[col] : 0.f;
#pragma unroll
        for (int rt = 0; rt < 2; ++rt) {
            int rowb = myrow0 + rt * 16 + g * 4;
#pragma unroll
            for (int j = 0; j < 4; ++j) {
                int row = rowb + j;
                if (row < N_NODES) {
                    if (col < 128)
                        out[(size_t)row * 128 + col] = acc[rt][nt][j] + bv;
                    else
                        Yn[(size_t)row * 128 + (col - 128)] = f2bf(acc[rt][nt][j]);
                }
            }
        }
    }
}

// ---------------- Aggregate: out[v] += (1/deg) * sum Yn[src] ----------------
__global__ __launch_bounds__(256) void agg2_k(const ushort* __restrict__ Yn,
                                              const int* __restrict__ offs,
                                              const int* __restrict__ count,
                                              const ushort* __restrict__ srclist,
                                              float* __restrict__ out) {
    int wid = blockIdx.x * 4 + (threadIdx.x >> 6);
    if (wid >= N_NODES) return;
    int lane = threadIdx.x & 63;
    int g = lane >> 4;          // edge slot within quad
    int c8 = (lane & 15) * 8;   // col base (8 bf16 = 16B)
    int off = offs[wid];
    int deg = count[wid];

    float acc0 = 0.f, acc1 = 0.f, acc2 = 0.f, acc3 = 0.f;
    float acc4 = 0.f, acc5 = 0.f, acc6 = 0.f, acc7 = 0.f;

#define ACC8(v)                                        \
    do {                                               \
        acc0 += bflo(v.x); acc1 += bfhi(v.x);          \
        acc2 += bflo(v.y); acc3 += bfhi(v.y);          \
        acc4 += bflo(v.z); acc5 += bfhi(v.z);          \
        acc6 += bflo(v.w); acc7 += bfhi(v.w);          \
    } while (0)

    for (int cb = 0; cb < deg; cb += 64) {
        int m = deg - cb;
        if (m > 64) m = 64;
        int sreg = (lane < m) ? (int)srclist[off + cb + lane] : 0;
        int j = 0;
        for (; j + 4 <= m; j += 4) {
            int s = __shfl(sreg, j + g);
            uint4 v = *(const uint4*)(Yn + (size_t)s * 128 + c8);
            ACC8(v);
        }
        if (j < m) {
            int jj = j + g;
            bool valid = jj < m;
            int s = __shfl(sreg, valid ? jj : j);
            uint4 v = *(const uint4*)(Yn + (size_t)s * 128 + c8);
            if (valid) ACC8(v);
        }
    }
#undef ACC8

#define RED(a) do { a += __shfl_xor(a, 16); a += __shfl_xor(a, 32); } while (0)
    RED(acc0); RED(acc1); RED(acc2); RED(acc3);
    RED(acc4); RED(acc5); RED(acc6); RED(acc7);
#undef RED

    if (lane < 16) {
        float scale = 1.0f / (float)(deg > 0 ? deg : 1);
        float* orow = out + (size_t)wid * 128 + c8;
        float4 o0 = *(const float4*)(orow);
        float4 o1 = *(const float4*)(orow + 4);
        o0.x += scale * acc0; o0.y += scale * acc1;
        o0.z += scale * acc2; o0.w += scale * acc3;
        o1.x += scale * acc4; o1.y += scale * acc5;
        o1.z += scale * acc6; o1.w += scale * acc7;
        *(float4*)(orow) = o0;
        *(float4*)(orow + 4) = o1;
    }
}

extern "C" void kernel_launch(void* const* d_in, const int* in_sizes, int n_in,
                              void* d_out, int out_size, void* d_ws, size_t ws_size,
                              hipStream_t stream) {
    const float* x       = (const float*)d_in[0];
    const float* W_self  = (const float*)d_in[1];
    const float* b_self  = (const float*)d_in[2];
    const float* W_neigh = (const float*)d_in[3];
    // d_in[4] = edge_w: unused (== 1/max(deg(dst),1), recomputed from counts)
    const int* src = (const int*)d_in[5];
    const int* dst = (const int*)d_in[6];
    float* out = (float*)d_out;

    // ws layout (bytes)
    char* ws = (char*)d_ws;
    ushort* Yn      = (ushort*)(ws);              // 12,800,000
    ushort* Wcat    = (ushort*)(ws + 12800000);   //     65,536
    int*    count   = (int*)(ws + 12865536);      //    200,000
    int*    offs    = (int*)(ws + 13065536);      //    200,000
    int*    bsum    = (int*)(ws + 13265536);      //      1,024
    ushort* epos    = (ushort*)(ws + 13266560);   //  1,600,000
    ushort* srclist = (ushort*)(ws + 14866560);   //  1,600,000

    const int nscan = (N_NODES + 255) / 256;  // 196
    const int nedge = (N_EDGES + 255) / 256;  // 3125

    hipMemsetAsync(count, 0, 200000, stream);

    cvtW_k<<<16, 256, 0, stream>>>(W_self, W_neigh, Wcat);
    degree_k<<<nedge, 256, 0, stream>>>(dst, count, epos);
    scanA_k<<<nscan, 256, 0, stream>>>(count, offs, bsum);
    scanBC_k<<<nscan, 256, 0, stream>>>(offs, bsum, nscan);
    fill_k<<<nedge, 256, 0, stream>>>(src, dst, offs, epos, srclist);

    // dense: out = x@Ws^T + b (fp32), Yn = x@Wn^T (bf16)
    mm_k<<<(N_NODES + 127) / 128, 256, 0, stream>>>(x, Wcat, b_self, out, Yn);

    // sparse: out[v] += (1/deg) * sum_{src->v} Yn[src]
    agg2_k<<<(N_NODES + 3) / 4, 256, 0, stream>>>(Yn, offs, count, srclist, out);
}

// Round 4
// 119.211 us; speedup vs baseline: 2.4331x; 1.0052x over previous
//
#include <hip/hip_runtime.h>
#include <hip/hip_bf16.h>

#define N_NODES 50000
#define N_EDGES 800000
#define DIM 128

typedef __attribute__((ext_vector_type(8))) short bf16x8;
typedef __attribute__((ext_vector_type(4))) float f32x4;

union BU8 { uint4 u; bf16x8 b; };

static __device__ __forceinline__ ushort f2bf(float f) {
    __hip_bfloat16 h = __float2bfloat16(f);
    return *reinterpret_cast<ushort*>(&h);
}
static __device__ __forceinline__ uint pack2(float a, float b) {
    return (uint)f2bf(a) | ((uint)f2bf(b) << 16);
}
static __device__ __forceinline__ float bflo(uint u) { return __uint_as_float(u << 16); }
static __device__ __forceinline__ float bfhi(uint u) { return __uint_as_float(u & 0xffff0000u); }

// ---------------- zero count (replaces runtime fillBuffer: it cost 42us!) ----
__global__ void zero_k(int4* __restrict__ p, int n4) {
    int i = blockIdx.x * blockDim.x + threadIdx.x;
    if (i < n4) p[i] = make_int4(0, 0, 0, 0);
}

// ---------------- W concat + convert: Wcat = [Ws ; Wn] bf16 ----------------
__global__ void cvtW_k(const float* __restrict__ Ws, const float* __restrict__ Wn,
                       ushort* __restrict__ Wcat) {
    int t = blockIdx.x * blockDim.x + threadIdx.x;  // 0..4095
    const float* srcp = (t < 2048) ? Ws : Wn;
    int i = (t & 2047) * 8;
    float4 a = *(const float4*)(srcp + i);
    float4 b = *(const float4*)(srcp + i + 4);
    uint4 r;
    r.x = pack2(a.x, a.y); r.y = pack2(a.z, a.w);
    r.z = pack2(b.x, b.y); r.w = pack2(b.z, b.w);
    *(uint4*)(Wcat + ((t < 2048) ? 0 : 16384) + i) = r;
}

// ---------------- CSR build (atomic-free fill) ----------------

__global__ void degree_k(const int* __restrict__ dst, int* __restrict__ count,
                         ushort* __restrict__ epos) {
    int e = blockIdx.x * blockDim.x + threadIdx.x;
    if (e < N_EDGES) {
        int pos = atomicAdd(&count[dst[e]], 1);
        epos[e] = (ushort)pos;
    }
}

__global__ void scanA_k(const int* __restrict__ count, int* __restrict__ offs,
                        int* __restrict__ bsum) {
    __shared__ int lds[256];
    int t = threadIdx.x;
    int i = blockIdx.x * 256 + t;
    int v = (i < N_NODES) ? count[i] : 0;
    lds[t] = v;
    __syncthreads();
    for (int s = 1; s < 256; s <<= 1) {
        int add = (t >= s) ? lds[t - s] : 0;
        __syncthreads();
        lds[t] += add;
        __syncthreads();
    }
    if (i < N_NODES) offs[i] = lds[t] - v;  // block-local exclusive
    if (t == 255) bsum[blockIdx.x] = lds[255];
}

// every block redundantly scans the 196 block sums, adds its prefix
__global__ void scanBC_k(int* __restrict__ offs, const int* __restrict__ bsum, int nb) {
    __shared__ int lds[256];
    int t = threadIdx.x;
    lds[t] = (t < nb) ? bsum[t] : 0;
    __syncthreads();
    for (int s = 1; s < 256; s <<= 1) {
        int add = (t >= s) ? lds[t - s] : 0;
        __syncthreads();
        lds[t] += add;
        __syncthreads();
    }
    int b = blockIdx.x;
    int prefix = (b == 0) ? 0 : lds[b - 1];
    int i = b * 256 + t;
    if (i < N_NODES) offs[i] += prefix;
}

__global__ void fill_k(const int* __restrict__ src, const int* __restrict__ dst,
                       const int* __restrict__ offs, const ushort* __restrict__ epos,
                       ushort* __restrict__ srclist) {
    int e = blockIdx.x * blockDim.x + threadIdx.x;
    if (e < N_EDGES) {
        int d = dst[e];
        srclist[offs[d] + (int)epos[e]] = (ushort)src[e];
    }
}

// ---------------- MFMA GEMM: out = x@Ws^T + b (fp32), Yn = x@Wn^T (bf16) --
__global__ __launch_bounds__(256, 2) void mm_k(const float* __restrict__ x,
                                               const ushort* __restrict__ Wcat,
                                               const float* __restrict__ bias,
                                               float* __restrict__ out,
                                               ushort* __restrict__ Yn) {
    __shared__ ushort wlds[32768];  // 64 KB
    int tid  = threadIdx.x;
    int lane = tid & 63;
    int w    = tid >> 6;
    int lr   = lane & 15;
    int g    = lane >> 4;            // k-group 0..3
    int myrow0 = blockIdx.x * 128 + w * 32;

    // ---- load A (fp32) & convert: 2 rowtiles x 4 kfrags ----
    bf16x8 a[2][4];
#pragma unroll
    for (int rt = 0; rt < 2; ++rt) {
        int row = myrow0 + rt * 16 + lr;
        bool ok = row < N_NODES;
        const float* ap = x + (size_t)row * 128;
#pragma unroll
        for (int kf = 0; kf < 4; ++kf) {
            float4 f0 = make_float4(0.f, 0.f, 0.f, 0.f), f1 = f0;
            if (ok) {
                f0 = *(const float4*)(ap + kf * 32 + g * 8);
                f1 = *(const float4*)(ap + kf * 32 + g * 8 + 4);
            }
            BU8 u;
            u.u.x = pack2(f0.x, f0.y); u.u.y = pack2(f0.z, f0.w);
            u.u.z = pack2(f1.x, f1.y); u.u.w = pack2(f1.z, f1.w);
            a[rt][kf] = u.b;
        }
    }

    // ---- stage Wcat into swizzled LDS: chunk c (16B) of row r at c^(r&7) ----
#pragma unroll
    for (int i = 0; i < 16; ++i) {
        int f = i * 256 + tid;
        int r = f >> 4, c = f & 15;
        uint4 v = *(const uint4*)(Wcat + r * 128 + c * 8);
        *(uint4*)(&wlds[r * 128 + ((c ^ (r & 7)) * 8)]) = v;
    }
    __syncthreads();

    // ---- K-loop over 16 col-tiles ----
    f32x4 acc[2][16];
#pragma unroll
    for (int rt = 0; rt < 2; ++rt)
#pragma unroll
        for (int nt = 0; nt < 16; ++nt) acc[rt][nt] = (f32x4){0.f, 0.f, 0.f, 0.f};

#pragma unroll
    for (int nt = 0; nt < 16; ++nt) {
        int row = nt * 16 + lr;
#pragma unroll
        for (int kf = 0; kf < 4; ++kf) {
            int chunk = kf * 4 + g;
            bf16x8 b = *(const bf16x8*)(&wlds[row * 128 + ((chunk ^ (lr & 7)) * 8)]);
            acc[0][nt] = __builtin_amdgcn_mfma_f32_16x16x32_bf16(a[0][kf], b, acc[0][nt], 0, 0, 0);
            acc[1][nt] = __builtin_amdgcn_mfma_f32_16x16x32_bf16(a[1][kf], b, acc[1][nt], 0, 0, 0);
        }
    }

    // ---- epilogue: col<128 -> out(+bias); col>=128 -> Yn bf16 ----
#pragma unroll
    for (int nt = 0; nt < 16; ++nt) {
        int col = nt * 16 + lr;
        float bv = (col < 128) ? bias[col] : 0.f;
#pragma unroll
        for (int rt = 0; rt < 2; ++rt) {
            int rowb = myrow0 + rt * 16 + g * 4;
#pragma unroll
            for (int j = 0; j < 4; ++j) {
                int row = rowb + j;
                if (row < N_NODES) {
                    if (col < 128)
                        out[(size_t)row * 128 + col] = acc[rt][nt][j] + bv;
                    else
                        Yn[(size_t)row * 128 + (col - 128)] = f2bf(acc[rt][nt][j]);
                }
            }
        }
    }
}

// ---------------- Aggregate: out[v] += (1/deg) * sum Yn[src] ----------------
__global__ __launch_bounds__(256) void agg2_k(const ushort* __restrict__ Yn,
                                              const int* __restrict__ offs,
                                              const int* __restrict__ count,
                                              const ushort* __restrict__ srclist,
                                              float* __restrict__ out) {
    int wid = blockIdx.x * 4 + (threadIdx.x >> 6);
    if (wid >= N_NODES) return;
    int lane = threadIdx.x & 63;
    int g = lane >> 4;          // edge slot within quad
    int c8 = (lane & 15) * 8;   // col base (8 bf16 = 16B)
    int off = offs[wid];
    int deg = count[wid];

    float acc0 = 0.f, acc1 = 0.f, acc2 = 0.f, acc3 = 0.f;
    float acc4 = 0.f, acc5 = 0.f, acc6 = 0.f, acc7 = 0.f;

#define ACC8(v)                                        \
    do {                                               \
        acc0 += bflo(v.x); acc1 += bfhi(v.x);          \
        acc2 += bflo(v.y); acc3 += bfhi(v.y);          \
        acc4 += bflo(v.z); acc5 += bfhi(v.z);          \
        acc6 += bflo(v.w); acc7 += bfhi(v.w);          \
    } while (0)

    for (int cb = 0; cb < deg; cb += 64) {
        int m = deg - cb;
        if (m > 64) m = 64;
        int sreg = (lane < m) ? (int)srclist[off + cb + lane] : 0;
        int j = 0;
        for (; j + 4 <= m; j += 4) {
            int s = __shfl(sreg, j + g);
            uint4 v = *(const uint4*)(Yn + (size_t)s * 128 + c8);
            ACC8(v);
        }
        if (j < m) {
            int jj = j + g;
            bool valid = jj < m;
            int s = __shfl(sreg, valid ? jj : j);
            uint4 v = *(const uint4*)(Yn + (size_t)s * 128 + c8);
            if (valid) ACC8(v);
        }
    }
#undef ACC8

#define RED(a) do { a += __shfl_xor(a, 16); a += __shfl_xor(a, 32); } while (0)
    RED(acc0); RED(acc1); RED(acc2); RED(acc3);
    RED(acc4); RED(acc5); RED(acc6); RED(acc7);
#undef RED

    if (lane < 16) {
        float scale = 1.0f / (float)(deg > 0 ? deg : 1);
        float* orow = out + (size_t)wid * 128 + c8;
        float4 o0 = *(const float4*)(orow);
        float4 o1 = *(const float4*)(orow + 4);
        o0.x += scale * acc0; o0.y += scale * acc1;
        o0.z += scale * acc2; o0.w += scale * acc3;
        o1.x += scale * acc4; o1.y += scale * acc5;
        o1.z += scale * acc6; o1.w += scale * acc7;
        *(float4*)(orow) = o0;
        *(float4*)(orow + 4) = o1;
    }
}

extern "C" void kernel_launch(void* const* d_in, const int* in_sizes, int n_in,
                              void* d_out, int out_size, void* d_ws, size_t ws_size,
                              hipStream_t stream) {
    const float* x       = (const float*)d_in[0];
    const float* W_self  = (const float*)d_in[1];
    const float* b_self  = (const float*)d_in[2];
    const float* W_neigh = (const float*)d_in[3];
    // d_in[4] = edge_w: unused (== 1/max(deg(dst),1), recomputed from counts)
    const int* src = (const int*)d_in[5];
    const int* dst = (const int*)d_in[6];
    float* out = (float*)d_out;

    // ws layout (bytes)
    char* ws = (char*)d_ws;
    ushort* Yn      = (ushort*)(ws);              // 12,800,000
    ushort* Wcat    = (ushort*)(ws + 12800000);   //     65,536
    int*    count   = (int*)(ws + 12865536);      //    200,000
    int*    offs    = (int*)(ws + 13065536);      //    200,000
    int*    bsum    = (int*)(ws + 13265536);      //      1,024
    ushort* epos    = (ushort*)(ws + 13266560);   //  1,600,000
    ushort* srclist = (ushort*)(ws + 14866560);   //  1,600,000

    const int nscan = (N_NODES + 255) / 256;  // 196
    const int nedge = (N_EDGES + 255) / 256;  // 3125

    // zero count: 50000 ints = 12500 int4
    zero_k<<<49, 256, 0, stream>>>((int4*)count, 12500);

    cvtW_k<<<16, 256, 0, stream>>>(W_self, W_neigh, Wcat);
    degree_k<<<nedge, 256, 0, stream>>>(dst, count, epos);
    scanA_k<<<nscan, 256, 0, stream>>>(count, offs, bsum);
    scanBC_k<<<nscan, 256, 0, stream>>>(offs, bsum, nscan);
    fill_k<<<nedge, 256, 0, stream>>>(src, dst, offs, epos, srclist);

    // dense: out = x@Ws^T + b (fp32), Yn = x@Wn^T (bf16)
    mm_k<<<(N_NODES + 127) / 128, 256, 0, stream>>>(x, Wcat, b_self, out, Yn);

    // sparse: out[v] += (1/deg) * sum_{src->v} Yn[src]
    agg2_k<<<(N_NODES + 3) / 4, 256, 0, stream>>>(Yn, offs, count, srclist, out);
}